// Round 4
// baseline (505.074 us; speedup 1.0000x reference)
//
#include <hip/hip_runtime.h>

// Izhikevich scan: 16384 chains x 2000 steps, 256 blocks x 4 waves.
// R4 post-mortem: izh invariant at ~243us across 3 store choreographies.
// Block write rate = 1.536MB/243us = 2.6 B/cyc/CU = 1.66 TB/s chip-wide --
// write-DRAIN-bound. Sustained write BW = in-flight bytes / latency; our
// flush-then-reuse structure self-capped in-flight at ~2.5KB/CU (compiler
// vmcnt at data-reg reuse). Poison-fill hits 6.3 TB/s with deep queues.
//
// R5: fill-kernel store pattern via a DEDICATED WRITER WAVE.
//   w0,w1,w2: redundant compute (planes s/v/u), NO global stores. Per 20-step
//             window: 20 ds_read inputs, 20 izh_steps, 20 ds_write to parity
//             ring. Also stage input chunks (global_load_lds, split 8/8/9,
//             private vmcnt(0) pre-satisfied by 5-window distance).
//   w3:       output writer: per window, 15 independent ds_read_b128 ->
//             global_store_dwordx4 (3 planes x 5 quads), fresh data regs =>
//             vmcnt reg-reuse wait lands a full window deep (~15KB in flight).
// Ring parity: computes write slot g&1 in window g; writer drains slot (g-1)&1
// => never same slot. lgkmcnt(0) before every raw s_barrier seals visibility.
// Barriers: 1 prologue + 100 windows, identical count in both branches.
//
// NUMERICS: exact numpy op order, fp contract off; values round-trip LDS
// bit-exactly.

#define NSTEPS 2000
#define NNEUR  512
#define BATCH  32
#define INPLANE 1024000u                       // NSTEPS*NNEUR per batch
#define PLANE  32768000u                       // BATCH*NSTEPS*NNEUR per out plane
#define CHUNK  100
#define NCHUNK (NSTEPS / CHUNK)                // 20
#define NG     (CHUNK / 4)                     // 25 staging groups of 4 steps
#define WIN    20                              // window (steps)
#define NWIN   (CHUNK / WIN)                   // 5 windows per chunk
#define NWINT  (NSTEPS / WIN)                  // 100 windows total

typedef const __attribute__((address_space(1))) unsigned GPtr;
typedef __attribute__((address_space(3))) unsigned LPtr;

__device__ __forceinline__ void izh_step(float i_t, float& v, float& u, float& s) {
#pragma clang fp contract(off)
    float t1 = 0.04f * v;
    t1 = t1 * v;
    float t2 = 5.0f * v;
    float acc = t1 + t2;
    acc = acc + 140.0f;
    acc = acc - u;
    acc = acc + i_t;
    float dv = acc * 0.5f;
    float t4 = 0.2f * v;
    t4 = t4 - u;
    t4 = 0.02f * t4;
    float du = t4 * 0.5f;
    v = v + dv;
    u = u + du;
    bool sp = (v >= 30.0f);
    s = sp ? 1.0f : 0.0f;
    v = sp ? -65.0f : v;
    u = sp ? (u + 8.0f) : u;
}

// Compute wave W (0=s,1=v,2=u): recurrence + ds_write to ring; stages its
// share of input chunks. No global stores.
template <int W>
__device__ __forceinline__ void run_compute(float (*lin)[CHUNK * 64],
                                            float (*ringP)[WIN][64],
                                            const float* gsrc, int lane) {
    constexpr int g0 = (W == 0) ? 0 : (W == 1) ? 8 : 16;
    constexpr int g1 = (W == 0) ? 8 : (W == 1) ? 16 : 25;

    // prologue: stage my share of chunk 0
#pragma unroll
    for (int g = g0; g < g1; ++g) {
        __builtin_amdgcn_global_load_lds((GPtr*)(gsrc + (size_t)(4 * g) * NNEUR),
                                         (LPtr*)(&lin[0][0] + g * 256), 16, 0, 0);
    }
    asm volatile("s_waitcnt vmcnt(0)" ::: "memory");
    asm volatile("s_barrier" ::: "memory");

    float v = -65.0f;
    float u = -13.0f;                          // B*C exactly

    for (int c = 0; c < NCHUNK; ++c) {
        const float* lbuf = &lin[c & 1][0];
        for (int ww = 0; ww < NWIN; ++ww) {
            if (ww == 0 && c + 1 < NCHUNK) {   // stage my share of chunk c+1
                const float* gs = gsrc + (size_t)(c + 1) * CHUNK * NNEUR;
                float* lb = &lin[(c + 1) & 1][0];
#pragma unroll
                for (int g = g0; g < g1; ++g) {
                    __builtin_amdgcn_global_load_lds((GPtr*)(gs + (size_t)(4 * g) * NNEUR),
                                                     (LPtr*)(lb + g * 256), 16, 0, 0);
                }
            }
            const int slot = (c * NWIN + ww) & 1;
            float ri[WIN];
#pragma unroll
            for (int j = 0; j < WIN; ++j) ri[j] = lbuf[(ww * WIN + j) * 64 + lane];
#pragma unroll
            for (int j = 0; j < WIN; ++j) {
                float s;
                izh_step(ri[j], v, u, s);
                ringP[slot][j][lane] = (W == 0) ? s : (W == 1) ? v : u;
            }
            asm volatile("s_waitcnt lgkmcnt(0)" ::: "memory");   // ds_writes visible
            if (ww == NWIN - 1)                                  // chunk c+1 resident
                asm volatile("s_waitcnt vmcnt(0)" ::: "memory"); // (pre-satisfied)
            asm volatile("s_barrier" ::: "memory");
        }
    }
}

// Writer: drain one 20-step window (3 planes) from the ring to global.
// 15 independent b128 reads -> 15 dwordx4 stores; fresh regs each call.
__device__ __forceinline__ void write_window(const float (*ring)[2][WIN][64],
                                             int slot, unsigned wstep0,
                                             int r0, int c4, unsigned obase,
                                             float* __restrict__ out) {
    float4 d[15];
#pragma unroll
    for (int P = 0; P < 3; ++P)
#pragma unroll
        for (int i = 0; i < 5; ++i)
            d[P * 5 + i] = *(const float4*)&ring[P][slot][r0 + 4 * i][c4];
#pragma unroll
    for (int P = 0; P < 3; ++P)
#pragma unroll
        for (int i = 0; i < 5; ++i) {
            size_t goff = (size_t)obase
                        + (size_t)(wstep0 + (unsigned)(r0 + 4 * i)) * NNEUR
                        + (size_t)(unsigned)c4;
            *(float4*)(out + (size_t)P * PLANE + goff) = d[P * 5 + i];
        }
}

__global__ __launch_bounds__(256, 1) void izh_kernel(const float* __restrict__ in,
                                                     float* __restrict__ out) {
    __shared__ float lin[2][CHUNK * 64];       // 51.2 KB input staging
    __shared__ float ring[3][2][WIN][64];      // 30.7 KB output ring (parity)

    const int tid  = threadIdx.x;
    const int w    = tid >> 6;                 // wave id 0..3
    const int lane = tid & 63;
    const unsigned n0 = (unsigned)((blockIdx.x * 64) & (NNEUR - 1)); // neuron base
    const unsigned b  = (unsigned)((unsigned)(blockIdx.x * 64) >> 9); // batch (uniform)
    const float* gsrc = in + (size_t)b * INPLANE
                           + (size_t)(lane >> 4) * NNEUR
                           + n0 + (size_t)(lane & 15) * 4;

    if (w == 3) {
        // ---- writer wave ----
        const int r0 = lane >> 4;              // step-in-quad
        const int c4 = (lane & 15) * 4;        // neuron quad base
        const unsigned obase = b * INPLANE + n0;

        asm volatile("s_barrier" ::: "memory");            // prologue
        for (int gw = 0; gw < NWINT; ++gw) {
            if (gw > 0)
                write_window(ring, (gw - 1) & 1, (unsigned)((gw - 1) * WIN),
                             r0, c4, obase, out);
            asm volatile("s_waitcnt lgkmcnt(0)" ::: "memory"); // ring reads done
            asm volatile("s_barrier" ::: "memory");
        }
        // final window (sealed by last barrier)
        write_window(ring, (NWINT - 1) & 1, (unsigned)((NWINT - 1) * WIN),
                     r0, c4, obase, out);
    } else {
        // ---- compute waves ----
        if (w == 0)      run_compute<0>(lin, ring[0], gsrc, lane);
        else if (w == 1) run_compute<1>(lin, ring[1], gsrc, lane);
        else             run_compute<2>(lin, ring[2], gsrc, lane);
    }
}

extern "C" void kernel_launch(void* const* d_in, const int* in_sizes, int n_in,
                              void* d_out, int out_size, void* d_ws, size_t ws_size,
                              hipStream_t stream) {
    const float* in = (const float*)d_in[0];
    float* out = (float*)d_out;
    izh_kernel<<<(BATCH * NNEUR) / 64, 256, 0, stream>>>(in, out);
}